// Round 1
// baseline (51.926 us; speedup 1.0000x reference)
//
#include <hip/hip_runtime.h>
#include <math.h>

#define BB 8
#define MM 1024
#define CC 32
#define NN (CC + MM)          // 1056
#define NROWS (BB * MM)       // 8192
#define MAXBLOCKS 256

__device__ __forceinline__ float wave_max(float v) {
#pragma unroll
    for (int o = 32; o > 0; o >>= 1) v = fmaxf(v, __shfl_down(v, o, 64));
    return v;
}
__device__ __forceinline__ float wave_sum(float v) {
#pragma unroll
    for (int o = 32; o > 0; o >>= 1) v += __shfl_down(v, o, 64);
    return v;
}
__device__ __forceinline__ int wave_sum_i(int v) {
#pragma unroll
    for (int o = 32; o > 0; o >>= 1) v += __shfl_down(v, o, 64);
    return v;
}

// Block (256 threads = 4 waves) reductions, result broadcast to all threads.
__device__ __forceinline__ float block_max(float v, float* s) {
    __syncthreads();                      // protect s from previous use
    v = wave_max(v);
    if ((threadIdx.x & 63) == 0) s[threadIdx.x >> 6] = v;
    __syncthreads();
    return fmaxf(fmaxf(s[0], s[1]), fmaxf(s[2], s[3]));
}
__device__ __forceinline__ float block_sum(float v, float* s) {
    __syncthreads();
    v = wave_sum(v);
    if ((threadIdx.x & 63) == 0) s[threadIdx.x >> 6] = v;
    __syncthreads();
    return (s[0] + s[1]) + (s[2] + s[3]);
}
__device__ __forceinline__ int block_sum_i(int v, int* s) {
    __syncthreads();
    v = wave_sum_i(v);
    if ((threadIdx.x & 63) == 0) s[threadIdx.x >> 6] = v;
    __syncthreads();
    return (s[0] + s[1]) + (s[2] + s[3]);
}

// ---- Kernel 1: per-block max over scores (float4 vectorized) ----
__global__ __launch_bounds__(256) void k_max1(const float4* __restrict__ sc4,
                                              int n4, float* __restrict__ bmax) {
    __shared__ float s[4];
    float m = -INFINITY;
    for (int i = blockIdx.x * blockDim.x + threadIdx.x; i < n4;
         i += gridDim.x * blockDim.x) {
        float4 v = sc4[i];
        m = fmaxf(fmaxf(m, fmaxf(v.x, v.y)), fmaxf(v.z, v.w));
    }
    m = block_max(m, s);
    if (threadIdx.x == 0) bmax[blockIdx.x] = m;
}

// ---- Kernel 2: 256 -> 1 max ----
__global__ __launch_bounds__(256) void k_max2(const float* __restrict__ bmax,
                                              float* __restrict__ gmax) {
    __shared__ float s[4];
    float m = bmax[threadIdx.x];
    m = block_max(m, s);
    if (threadIdx.x == 0) gmax[0] = m;
}

// ---- Kernel 3: one block per (b,m) row ----
__global__ __launch_bounds__(256) void k_rowloss(
        const float* __restrict__ scores,
        const int* __restrict__ link_targets,
        const int* __restrict__ cand_len,
        const int* __restrict__ cids,
        const int* __restrict__ lengths,
        const float* __restrict__ gmax,
        float* __restrict__ row_loss) {
    __shared__ float s_masked[NN];
    __shared__ unsigned char s_tgt[NN];
    __shared__ float s_redf[4];
    __shared__ int s_redi[4];

    const int row = blockIdx.x;
    const int b = row >> 10;        // MM = 1024
    const int m = row & 1023;

    const float* srow = scores + (size_t)row * NN;
    const int* lt = link_targets + (size_t)row * CC;
    const int* cidrow = cids + b * MM;

    const int clen = cand_len[row];
    const int cid_i = cidrow[m];
    const bool in_range = m < lengths[b];
    const float constant = gmax[0] + 100000.0f;

    // Pass 1: masked scores + target bits -> LDS; row max; target count.
    float lmax = -INFINITY;
    int lcnt = 0;
    for (int k = threadIdx.x; k < NN; k += 256) {
        float sc = srow[k];
        bool vis, tgt;
        if (k < CC) {
            vis = (k < clen);
            tgt = vis && (lt[k] != 0);
        } else {
            int j = k - CC;
            vis = true;
            tgt = (cid_i >= 0) && (j != m) && (cidrow[j] == cid_i);
        }
        float mv = vis ? sc : sc - constant;
        s_masked[k] = mv;
        s_tgt[k] = (unsigned char)tgt;
        lmax = fmaxf(lmax, mv);
        lcnt += (int)tgt;
    }
    float rowmax = block_max(lmax, s_redf);
    int cnt = block_sum_i(lcnt, s_redi);

    __syncthreads();
    if (threadIdx.x == 0 && cnt == 0 && in_range) s_tgt[CC + m] = 1;
    __syncthreads();

    // Pass 2: softmax denominator + adjusted max.
    float lsum = 0.0f, ladjmax = -INFINITY;
    for (int k = threadIdx.x; k < NN; k += 256) {
        float mv = s_masked[k];
        lsum += __expf(mv - rowmax);
        float adj = mv - (s_tgt[k] ? 0.0f : 100000.0f);
        ladjmax = fmaxf(ladjmax, adj);
    }
    float Z = block_sum(lsum, s_redf);
    float adjmax = block_max(ladjmax, s_redf);

    // Pass 3: adjusted denominator.
    float lsumadj = 0.0f;
    for (int k = threadIdx.x; k < NN; k += 256) {
        float adj = s_masked[k] - (s_tgt[k] ? 0.0f : 100000.0f);
        lsumadj += __expf(adj - adjmax);
    }
    float Zadj = block_sum(lsumadj, s_redf);

    if (threadIdx.x == 0) {
        float loss = (rowmax + logf(Z)) - (adjmax + logf(Zadj));
        row_loss[row] = in_range ? loss : 0.0f;
    }
}

// ---- Kernel 4: deterministic 8192 -> 1 sum ----
__global__ __launch_bounds__(256) void k_finalsum(const float* __restrict__ row_loss,
                                                  float* __restrict__ out) {
    __shared__ float s[4];
    float v = 0.0f;
    for (int i = threadIdx.x; i < NROWS; i += 256) v += row_loss[i];
    v = block_sum(v, s);
    if (threadIdx.x == 0) out[0] = v;
}

extern "C" void kernel_launch(void* const* d_in, const int* in_sizes, int n_in,
                              void* d_out, int out_size, void* d_ws, size_t ws_size,
                              hipStream_t stream) {
    const float* scores = (const float*)d_in[0];
    const int* link_targets = (const int*)d_in[1];
    const int* cand_len = (const int*)d_in[2];
    const int* cids = (const int*)d_in[3];
    const int* lengths = (const int*)d_in[4];
    float* out = (float*)d_out;

    float* ws = (float*)d_ws;
    float* bmax = ws;                 // [256]
    float* gmax = ws + MAXBLOCKS;     // [1]
    float* row_loss = ws + 512;       // [8192]

    const int n_total = BB * MM * NN; // 8,650,752 (divisible by 4)
    const int n4 = n_total / 4;

    k_max1<<<MAXBLOCKS, 256, 0, stream>>>((const float4*)scores, n4, bmax);
    k_max2<<<1, 256, 0, stream>>>(bmax, gmax);
    k_rowloss<<<NROWS, 256, 0, stream>>>(scores, link_targets, cand_len, cids,
                                         lengths, gmax, row_loss);
    k_finalsum<<<1, 256, 0, stream>>>(row_loss, out);
}

// Round 2
// 23.824 us; speedup vs baseline: 2.1795x; 2.1795x over previous
//
#include <hip/hip_runtime.h>
#include <math.h>

#define BB 8
#define MM 1024
#define CC 32
#define NN (CC + MM)          // 1056
#define NROWS (BB * MM)       // 8192
#define NEGINF (-INFINITY)

// ---- Kernel 1: one wave (64 lanes) per (b,m) row; all data in registers ----
// Layout per lane: v[0..15]  = 4 coref float4 chunks (j = 4*lane + 256*c)
//                  v[16..19] = linker float4 (lanes 0..7 only, k = 4*lane)
__global__ __launch_bounds__(256) void k_rowloss(
        const float* __restrict__ scores,
        const int* __restrict__ link_targets,
        const int* __restrict__ cand_len,
        const int* __restrict__ cids,
        const int* __restrict__ lengths,
        float* __restrict__ row_loss) {
    const int lane = threadIdx.x & 63;
    const int row = (blockIdx.x << 2) + (threadIdx.x >> 6);
    const int b = row >> 10;          // MM = 1024
    const int m = row & 1023;

    const float* srow = scores + (size_t)row * NN;
    const int* cidrow = cids + (b << 10);
    const int clen = cand_len[row];
    const int cid_i = cidrow[m];

    float v[20];
    bool tg[20];

    float rmax = NEGINF;   // max over visible entries
    float tmax = NEGINF;   // max over target entries
    int cnt = 0;           // number of (real) targets

    // Coref block: fully visible.
#pragma unroll
    for (int c = 0; c < 4; ++c) {
        const int j0 = (c << 8) + (lane << 2);
        const float4 f = *(const float4*)(srow + CC + j0);
        const int4 cd = *(const int4*)(cidrow + j0);
        v[c * 4 + 0] = f.x;
        v[c * 4 + 1] = f.y;
        v[c * 4 + 2] = f.z;
        v[c * 4 + 3] = f.w;
        tg[c * 4 + 0] = (cid_i >= 0) && (cd.x == cid_i) && (j0 + 0 != m);
        tg[c * 4 + 1] = (cid_i >= 0) && (cd.y == cid_i) && (j0 + 1 != m);
        tg[c * 4 + 2] = (cid_i >= 0) && (cd.z == cid_i) && (j0 + 2 != m);
        tg[c * 4 + 3] = (cid_i >= 0) && (cd.w == cid_i) && (j0 + 3 != m);
    }

    // Linker block: lanes 0..7 hold k = 4*lane .. 4*lane+3.
    if (lane < 8) {
        const int k0 = lane << 2;
        const float4 f = *(const float4*)(srow + k0);
        const int4 t4 = *(const int4*)(link_targets + (size_t)row * CC + k0);
        const bool vis0 = (k0 + 0) < clen;
        const bool vis1 = (k0 + 1) < clen;
        const bool vis2 = (k0 + 2) < clen;
        const bool vis3 = (k0 + 3) < clen;
        v[16] = vis0 ? f.x : NEGINF;
        v[17] = vis1 ? f.y : NEGINF;
        v[18] = vis2 ? f.z : NEGINF;
        v[19] = vis3 ? f.w : NEGINF;
        tg[16] = vis0 && (t4.x != 0);
        tg[17] = vis1 && (t4.y != 0);
        tg[18] = vis2 && (t4.z != 0);
        tg[19] = vis3 && (t4.w != 0);
    } else {
#pragma unroll
        for (int i = 16; i < 20; ++i) { v[i] = NEGINF; tg[i] = false; }
    }

    // Per-lane maxima and target count.
#pragma unroll
    for (int i = 0; i < 20; ++i) {
        rmax = fmaxf(rmax, v[i]);
        if (tg[i]) { tmax = fmaxf(tmax, v[i]); cnt++; }
    }

    // Wave butterfly reductions (64 lanes).
#pragma unroll
    for (int o = 32; o > 0; o >>= 1) {
        rmax = fmaxf(rmax, __shfl_xor(rmax, o, 64));
        tmax = fmaxf(tmax, __shfl_xor(tmax, o, 64));
        cnt += __shfl_xor(cnt, o, 64);
    }

    // Denominators (invisible entries: exp(-inf) == 0, exact).
    float s = 0.0f, st = 0.0f;
#pragma unroll
    for (int i = 0; i < 20; ++i) {
        s += __expf(v[i] - rmax);
        if (tg[i]) st += __expf(v[i] - tmax);
    }
#pragma unroll
    for (int o = 32; o > 0; o >>= 1) {
        s += __shfl_xor(s, o, 64);
        st += __shfl_xor(st, o, 64);
    }

    if (lane == 0) {
        const bool in_range = m < lengths[b];
        float lse = rmax + logf(s);
        float lse_t;
        if (cnt > 0) {
            lse_t = tmax + logf(st);
        } else {
            // singleton: target = self-link diag entry (always visible)
            lse_t = srow[CC + m];
        }
        row_loss[row] = in_range ? (lse - lse_t) : 0.0f;
    }
}

// ---- Kernel 2: deterministic 8192 -> 1 sum ----
__global__ __launch_bounds__(256) void k_finalsum(const float* __restrict__ row_loss,
                                                  float* __restrict__ out) {
    __shared__ float sred[4];
    float vsum = 0.0f;
    for (int i = threadIdx.x; i < NROWS; i += 256) vsum += row_loss[i];
#pragma unroll
    for (int o = 32; o > 0; o >>= 1) vsum += __shfl_down(vsum, o, 64);
    if ((threadIdx.x & 63) == 0) sred[threadIdx.x >> 6] = vsum;
    __syncthreads();
    if (threadIdx.x == 0) out[0] = (sred[0] + sred[1]) + (sred[2] + sred[3]);
}

extern "C" void kernel_launch(void* const* d_in, const int* in_sizes, int n_in,
                              void* d_out, int out_size, void* d_ws, size_t ws_size,
                              hipStream_t stream) {
    const float* scores = (const float*)d_in[0];
    const int* link_targets = (const int*)d_in[1];
    const int* cand_len = (const int*)d_in[2];
    const int* cids = (const int*)d_in[3];
    const int* lengths = (const int*)d_in[4];
    float* out = (float*)d_out;

    float* row_loss = (float*)d_ws;   // [8192]

    k_rowloss<<<NROWS / 4, 256, 0, stream>>>(scores, link_targets, cand_len,
                                             cids, lengths, row_loss);
    k_finalsum<<<1, 256, 0, stream>>>(row_loss, out);
}